// Round 8
// baseline (3314.799 us; speedup 1.0000x reference)
//
#include <hip/hip_runtime.h>
#include <math.h>

#define PI_F 3.14159265358979323846f

typedef __attribute__((ext_vector_type(8))) short bf16x8;
typedef __attribute__((ext_vector_type(4))) float f32x4;
typedef __attribute__((ext_vector_type(8))) unsigned short u16x8;

// fp32 -> bf16 round-to-nearest-even
__device__ inline unsigned short f2bf(float f){
  unsigned int b = __float_as_uint(f);
  b += 0x7FFFu + ((b >> 16) & 1u);
  return (unsigned short)(b >> 16);
}

__device__ inline float clamp1(float v){ return fminf(1.0f, fmaxf(-1.0f, v)); }

__device__ inline void tri_decode(int t, int& bi, int& bj){
  bi = (int)((sqrtf(8.0f * t + 1.0f) - 1.0f) * 0.5f);
  while ((bi + 1) * (bi + 2) / 2 <= t) ++bi;
  while (bi * (bi + 1) / 2 > t) --bi;
  bj = t - bi * (bi + 1) / 2;
}

// ---------------------------------------------------------------------------
// 0) X (fp32) -> Xbf (bf16)
// ---------------------------------------------------------------------------
__global__ void convert_bf16(const float* __restrict__ X,
                             unsigned short* __restrict__ Xb, long total){
  long i = ((long)blockIdx.x * 256 + threadIdx.x) * 8;
  if (i >= total) return;
  float4 a = *reinterpret_cast<const float4*>(X + i);
  float4 b = *reinterpret_cast<const float4*>(X + i + 4);
  u16x8 o;
  o[0] = f2bf(a.x); o[1] = f2bf(a.y); o[2] = f2bf(a.z); o[3] = f2bf(a.w);
  o[4] = f2bf(b.x); o[5] = f2bf(b.y); o[6] = f2bf(b.z); o[7] = f2bf(b.w);
  *reinterpret_cast<u16x8*>(Xb + i) = o;
}

// ---------------------------------------------------------------------------
// 1a) Symmetric split-K gram, BK=64, XOR-swizzled LDS (kills the 8-way bank
//     conflict on MFMA fragment reads; SQ_LDS_BANK_CONFLICT was 8.9e6).
//     LDS chunk c of row r holds global 16B-chunk c^(r&7); staging achieves
//     this by permuting the SOURCE chunk per lane (dest is lane-contiguous
//     as required by global_load_lds). Fragment reader: chunk = g^(row&7),
//     g = ks*4+q -> 2-way bank aliasing only (free).
// ---------------------------------------------------------------------------
__global__ __launch_bounds__(256) void gram_sym(const unsigned short* __restrict__ Xb,
                                                float* __restrict__ P,
                                                int K, int TP, int Ssplit, int Kc){
  const int b = blockIdx.x;
  const int t = b % TP;
  const int s = b / TP;
  int bi, bj; tri_decode(t, bi, bj);
  const int ti = bj, tj = bi;            // ti <= tj
  const int ks0 = s * Kc;

  __shared__ unsigned short Ab[128 * 64];   // 16 KB
  __shared__ unsigned short Bb[128 * 64];
  const int tid = threadIdx.x, lane = tid & 63, w = tid >> 6;
  const int wi = (w >> 1) * 64, wj = (w & 1) * 64;
  const int m16 = lane & 15, q = lane >> 4;

  f32x4 acc[4][4];
#pragma unroll
  for (int a = 0; a < 4; ++a)
#pragma unroll
    for (int b2 = 0; b2 < 4; ++b2) acc[a][b2] = (f32x4){0.f, 0.f, 0.f, 0.f};

  const unsigned short* Ag = Xb + (size_t)(ti * 128) * K;
  const unsigned short* Bg = Xb + (size_t)(tj * 128) * K;
  const int srow = lane >> 3;                       // 0..7
  const int schunk = ((lane & 7) ^ srow) * 8;       // swizzled source chunk

  for (int k0 = ks0; k0 < ks0 + Kc; k0 += 64){
    __syncthreads();
#pragma unroll
    for (int r = 0; r < 4; ++r){
      int row = w * 32 + r * 8 + srow;
      __builtin_amdgcn_global_load_lds(
        (const __attribute__((address_space(1))) void*)(Ag + (size_t)row * K + k0 + schunk),
        (__attribute__((address_space(3))) void*)(Ab + (w * 32 + r * 8) * 64),
        16, 0, 0);
      __builtin_amdgcn_global_load_lds(
        (const __attribute__((address_space(1))) void*)(Bg + (size_t)row * K + k0 + schunk),
        (__attribute__((address_space(3))) void*)(Bb + (w * 32 + r * 8) * 64),
        16, 0, 0);
    }
    __syncthreads();
#pragma unroll
    for (int ks = 0; ks < 2; ++ks){
      bf16x8 af[4], bfr[4];
#pragma unroll
      for (int a = 0; a < 4; ++a){
        int row = wi + a * 16 + m16;
        int ch = ((ks * 4 + q) ^ (row & 7)) * 8;
        af[a] = *reinterpret_cast<const bf16x8*>(&Ab[row * 64 + ch]);
      }
#pragma unroll
      for (int b2 = 0; b2 < 4; ++b2){
        int row = wj + b2 * 16 + m16;
        int ch = ((ks * 4 + q) ^ (row & 7)) * 8;
        bfr[b2] = *reinterpret_cast<const bf16x8*>(&Bb[row * 64 + ch]);
      }
#pragma unroll
      for (int a = 0; a < 4; ++a)
#pragma unroll
        for (int b2 = 0; b2 < 4; ++b2)
          acc[a][b2] = __builtin_amdgcn_mfma_f32_16x16x32_bf16(af[a], bfr[b2], acc[a][b2], 0, 0, 0);
    }
  }

  float* Pt = P + ((size_t)(s * TP + t) << 14);
#pragma unroll
  for (int a = 0; a < 4; ++a)
#pragma unroll
    for (int b2 = 0; b2 < 4; ++b2)
#pragma unroll
      for (int r = 0; r < 4; ++r){
        int row = wi + a * 16 + q * 4 + r;
        int col = wj + b2 * 16 + m16;
        Pt[row * 128 + col] = acc[a][b2][r];
      }
}

// Sum partials, scale+clamp, write tile and (via LDS transpose) its mirror.
__global__ __launch_bounds__(256) void gram_reduce(const float* __restrict__ P,
                                                   float* __restrict__ S,
                                                   int n, int TP, int Ssplit,
                                                   float invK){
  const int t = blockIdx.x;
  int bi, bj; tri_decode(t, bi, bj);
  const int ti = bj, tj = bi;
  const int tid = threadIdx.x;
  __shared__ float Ls[128][129];
  const float* Pt = P + ((size_t)t << 14);
  const size_t pstride = (size_t)TP << 14;
#pragma unroll
  for (int it = 0; it < 16; ++it){
    int off = it * 1024 + tid * 4;
    int r = off >> 7, c = off & 127;
    float4 v = *reinterpret_cast<const float4*>(Pt + off);
    for (int s = 1; s < Ssplit; ++s){
      float4 u = *reinterpret_cast<const float4*>(Pt + s * pstride + off);
      v.x += u.x; v.y += u.y; v.z += u.z; v.w += u.w;
    }
    v.x = clamp1(v.x * invK); v.y = clamp1(v.y * invK);
    v.z = clamp1(v.z * invK); v.w = clamp1(v.w * invK);
    *reinterpret_cast<float4*>(S + (size_t)(ti * 128 + r) * n + tj * 128 + c) = v;
    *reinterpret_cast<float4*>(&Ls[r][c]) = v;
  }
  if (ti == tj) return;
  __syncthreads();
#pragma unroll
  for (int it = 0; it < 16; ++it){
    int off = it * 1024 + tid * 4;
    int m = off >> 7, cc = off & 127;
    float4 v = { Ls[cc + 0][m], Ls[cc + 1][m], Ls[cc + 2][m], Ls[cc + 3][m] };
    *reinterpret_cast<float4*>(S + (size_t)(tj * 128 + m) * n + ti * 128 + cc) = v;
  }
}

// ---------------------------------------------------------------------------
// 1b) Monolithic gram from bf16 (fallback when partial buffers don't fit).
// ---------------------------------------------------------------------------
__global__ __launch_bounds__(256) void gram_bf16(const unsigned short* __restrict__ Xb,
                                                 float* __restrict__ S, int n, int K){
  const int tiles = n >> 7;
  int b = blockIdx.x, ti, tj;
  if (tiles == 16){
    int xcd = b & 7, s2 = b >> 3;
    ti = ((xcd >> 1) << 2) | (s2 & 3);
    tj = ((xcd & 1) << 3) | (s2 >> 2);
  } else { ti = b / tiles; tj = b - ti * tiles; }

  __shared__ unsigned short Ab[128 * 32];
  __shared__ unsigned short Bb[128 * 32];
  const int tid = threadIdx.x, lane = tid & 63, w = tid >> 6;
  const int wi = (w >> 1) * 64, wj = (w & 1) * 64;
  const int m16 = lane & 15, q = lane >> 4;

  f32x4 acc[4][4];
#pragma unroll
  for (int a = 0; a < 4; ++a)
#pragma unroll
    for (int b2 = 0; b2 < 4; ++b2) acc[a][b2] = (f32x4){0.f, 0.f, 0.f, 0.f};

  const unsigned short* Ag = Xb + (size_t)(ti * 128) * K;
  const unsigned short* Bg = Xb + (size_t)(tj * 128) * K;
  const int srow = lane >> 2;
  const int scol = (lane & 3) * 8;

  for (int k0 = 0; k0 < K; k0 += 32){
    __syncthreads();
#pragma unroll
    for (int r = 0; r < 2; ++r){
      int row = w * 32 + r * 16 + srow;
      __builtin_amdgcn_global_load_lds(
        (const __attribute__((address_space(1))) void*)(Ag + (size_t)row * K + k0 + scol),
        (__attribute__((address_space(3))) void*)(Ab + w * 1024 + r * 512),
        16, 0, 0);
      __builtin_amdgcn_global_load_lds(
        (const __attribute__((address_space(1))) void*)(Bg + (size_t)row * K + k0 + scol),
        (__attribute__((address_space(3))) void*)(Bb + w * 1024 + r * 512),
        16, 0, 0);
    }
    __syncthreads();
    bf16x8 af[4], bfr[4];
#pragma unroll
    for (int a = 0; a < 4; ++a)
      af[a] = *reinterpret_cast<const bf16x8*>(&Ab[(wi + a * 16 + m16) * 32 + q * 8]);
#pragma unroll
    for (int b2 = 0; b2 < 4; ++b2)
      bfr[b2] = *reinterpret_cast<const bf16x8*>(&Bb[(wj + b2 * 16 + m16) * 32 + q * 8]);
#pragma unroll
    for (int a = 0; a < 4; ++a)
#pragma unroll
      for (int b2 = 0; b2 < 4; ++b2)
        acc[a][b2] = __builtin_amdgcn_mfma_f32_16x16x32_bf16(af[a], bfr[b2], acc[a][b2], 0, 0, 0);
  }

  const float invK = 1.0f / (float)K;
#pragma unroll
  for (int a = 0; a < 4; ++a)
#pragma unroll
    for (int b2 = 0; b2 < 4; ++b2)
#pragma unroll
      for (int r = 0; r < 4; ++r){
        int row = ti * 128 + wi + a * 16 + q * 4 + r;
        int col = tj * 128 + wj + b2 * 16 + m16;
        S[(size_t)row * n + col] = clamp1(acc[a][b2][r] * invK);
      }
}

// ---------------------------------------------------------------------------
// 1c) Fallback gram (fp32 input, in-kernel conversion).
// ---------------------------------------------------------------------------
__global__ __launch_bounds__(256) void gram_kernel(const float* __restrict__ X,
                                                   float* __restrict__ S,
                                                   int n, int K){
  const int tiles = n >> 7;
  int b = blockIdx.x, ti, tj;
  ti = b / tiles; tj = b - ti * tiles;

  __shared__ unsigned short Ab[128 * 32];
  __shared__ unsigned short Bb[128 * 32];

  const int tid = threadIdx.x;
  const int lane = tid & 63;
  const int w = tid >> 6;
  const int wi = (w >> 1) * 64, wj = (w & 1) * 64;
  const int m16 = lane & 15, q = lane >> 4;

  f32x4 acc[4][4];
#pragma unroll
  for (int a = 0; a < 4; ++a)
#pragma unroll
    for (int b2 = 0; b2 < 4; ++b2) acc[a][b2] = (f32x4){0.f, 0.f, 0.f, 0.f};

  const float* Abase = X + (size_t)ti * 128 * K;
  const float* Bbase = X + (size_t)tj * 128 * K;
  const int strow = tid >> 3;
  const int stc = (tid & 7) * 4;

  float4 ra[4], rb[4];
  for (int k0 = 0; k0 < K; k0 += 32){
#pragma unroll
    for (int r = 0; r < 4; ++r){
      int row = r * 32 + strow;
      ra[r] = *reinterpret_cast<const float4*>(Abase + (size_t)row * K + k0 + stc);
      rb[r] = *reinterpret_cast<const float4*>(Bbase + (size_t)row * K + k0 + stc);
    }
    __syncthreads();
#pragma unroll
    for (int r = 0; r < 4; ++r){
      int row = r * 32 + strow;
      int base = row * 32 + stc;
      ushort4 ua, ub;
      ua.x = f2bf(ra[r].x); ua.y = f2bf(ra[r].y); ua.z = f2bf(ra[r].z); ua.w = f2bf(ra[r].w);
      ub.x = f2bf(rb[r].x); ub.y = f2bf(rb[r].y); ub.z = f2bf(rb[r].z); ub.w = f2bf(rb[r].w);
      *reinterpret_cast<ushort4*>(&Ab[base]) = ua;
      *reinterpret_cast<ushort4*>(&Bb[base]) = ub;
    }
    __syncthreads();
    bf16x8 af[4], bfv[4];
#pragma unroll
    for (int a = 0; a < 4; ++a)
      af[a] = *reinterpret_cast<const bf16x8*>(&Ab[(wi + a * 16 + m16) * 32 + q * 8]);
#pragma unroll
    for (int b2 = 0; b2 < 4; ++b2)
      bfv[b2] = *reinterpret_cast<const bf16x8*>(&Bb[(wj + b2 * 16 + m16) * 32 + q * 8]);
#pragma unroll
    for (int a = 0; a < 4; ++a)
#pragma unroll
      for (int b2 = 0; b2 < 4; ++b2)
        acc[a][b2] = __builtin_amdgcn_mfma_f32_16x16x32_bf16(af[a], bfv[b2], acc[a][b2], 0, 0, 0);
  }

  const float invK = 1.0f / (float)K;
#pragma unroll
  for (int a = 0; a < 4; ++a)
#pragma unroll
    for (int b2 = 0; b2 < 4; ++b2)
#pragma unroll
      for (int r = 0; r < 4; ++r){
        int row = ti * 128 + wi + a * 16 + q * 4 + r;
        int col = tj * 128 + wj + b2 * 16 + m16;
        S[(size_t)row * n + col] = clamp1(acc[a][b2][r] * invK);
      }
}

// ---------------------------------------------------------------------------
// 2) arc-cosine kernel step
// ---------------------------------------------------------------------------
__global__ void diag_copy(const float* __restrict__ S, float* __restrict__ d, int n){
  int i = blockIdx.x * blockDim.x + threadIdx.x;
  if (i < n) d[i] = S[(size_t)i * n + i];
}

__global__ void step_kernel(float* __restrict__ S, const float* __restrict__ d,
                            const float* __restrict__ alphap, int n){
  int j = blockIdx.x * blockDim.x + threadIdx.x;
  int i = blockIdx.y;
  if (j >= n) return;
  float a2 = alphap[0] * alphap[0];
  size_t idx = (size_t)i * n + j;
  float s = S[idx];
  float cross = sqrtf(d[i] * d[j]);
  float m = clamp1(s / cross);
  float qq = 1.0f - m * m;
  float sq, ac;
  if (qq > 0.0f){ sq = sqrtf(qq); ac = acosf(m); }
  else          { sq = 0.0f;      ac = (m > 0.0f) ? 0.0f : PI_F; }
  float f = (sq + m * (PI_F - ac)) / PI_F;
  float t = cross * f;
  S[idx] = clamp1((s + a2 * t) / (1.0f + a2));
}

// ---------------------------------------------------------------------------
// 3a) Cholesky diagonal block — rank-8 panels; sweep restructured with
//     explicit 4-row groups (12 independent LDS loads issued before any use)
//     to break the exposed-latency serialization that kept rounds 4-6 at
//     ~150 us. m = rows per batch is always a multiple of 8 -> no tails.
// ---------------------------------------------------------------------------
__global__ __launch_bounds__(256) void chol_diag(float* __restrict__ S,
                                                 float* __restrict__ Linv,
                                                 int n, int s){
  __shared__ float As[128][132];
  __shared__ float Iv[128][132];
  __shared__ __align__(16) float cst[128][12];
  __shared__ float rst[8][128];
  const int tid = threadIdx.x;
  float* blk = S + (size_t)s * 128 * n + (size_t)s * 128;
#pragma unroll
  for (int it = 0; it < 16; ++it){
    int f = it * 1024 + tid * 4;
    int r = f >> 7, c = f & 127;
    float4 v = *reinterpret_cast<const float4*>(blk + (size_t)r * n + c);
    *reinterpret_cast<float4*>(&As[r][c]) = v;
    float4 e = {0.f, 0.f, 0.f, 0.f};
    if (r >= c && r < c + 4) ((float*)&e)[r - c] = 1.0f;
    *reinterpret_cast<float4*>(&Iv[r][c]) = e;
  }
  __syncthreads();

  const int lane = tid & 63;
  const int wv = tid >> 6;        // 0..3
  const int c0 = 2 * lane, c1 = 2 * lane + 1;

  for (int b = 0; b < 16; ++b){
    const int j0 = b * 8;
    // ---- STAGE ----
    {
      float T[8][8], invd[8];
#pragma unroll
      for (int u = 0; u < 8; ++u)
#pragma unroll
        for (int w = 0; w < 8; ++w) T[u][w] = 0.0f;
#pragma unroll
      for (int u = 0; u < 8; ++u)
#pragma unroll
        for (int w = 0; w < 8; ++w) if (w <= u) T[u][w] = As[j0 + u][j0 + w];
#pragma unroll
      for (int w = 0; w < 8; ++w){
        float dv = sqrtf(T[w][w]);
        invd[w] = 1.0f / dv;
        T[w][w] = dv;
#pragma unroll
        for (int u = 0; u < 8; ++u) if (u > w) T[u][w] *= invd[w];
#pragma unroll
        for (int u = 0; u < 8; ++u)
#pragma unroll
          for (int v = 0; v < 8; ++v)
            if (u > w && v > w && v <= u) T[u][v] -= T[u][w] * T[v][w];
      }
      if (tid < 128){
        int r = tid;
        if (r >= j0){
          float l[8];
          if (r < j0 + 8){
            int p = r - j0;
#pragma unroll
            for (int w = 0; w < 8; ++w) l[w] = (w <= p) ? T[p][w] : 0.0f;
          } else {
            *(float4*)&l[0] = *reinterpret_cast<const float4*>(&As[r][j0]);
            *(float4*)&l[4] = *reinterpret_cast<const float4*>(&As[r][j0 + 4]);
#pragma unroll
            for (int w = 0; w < 8; ++w){
#pragma unroll
              for (int u = 0; u < 8; ++u) if (u < w) l[w] -= l[u] * T[w][u];
              l[w] *= invd[w];
            }
          }
#pragma unroll
          for (int w = 0; w < 8; ++w){ cst[r][w] = l[w]; As[r][j0 + w] = l[w]; }
        }
      } else {
        int c = tid - 128;
        float yv[8];
#pragma unroll
        for (int w = 0; w < 8; ++w) yv[w] = Iv[j0 + w][c];
#pragma unroll
        for (int w = 0; w < 8; ++w){
#pragma unroll
          for (int u = 0; u < 8; ++u) if (u < w) yv[w] -= T[w][u] * yv[u];
          yv[w] *= invd[w];
        }
#pragma unroll
        for (int w = 0; w < 8; ++w){
          rst[w][c] = yv[w];
          if (c <= j0 + w) Iv[j0 + w][c] = yv[w];
        }
      }
    }
    __syncthreads();
    // ---- SWEEP: rank-8 trailing update, 4-row groups for ILP ----
    if (j0 + 8 < 128){
      const int rbeg = j0 + 8;
      if (wv < 2){
        float va0[8], va1[8];
        *(float4*)&va0[0] = *reinterpret_cast<const float4*>(&cst[c0][0]);
        *(float4*)&va0[4] = *reinterpret_cast<const float4*>(&cst[c0][4]);
        *(float4*)&va1[0] = *reinterpret_cast<const float4*>(&cst[c1][0]);
        *(float4*)&va1[4] = *reinterpret_cast<const float4*>(&cst[c1][4]);
        if (c0 < rbeg){
#pragma unroll
          for (int w = 0; w < 8; ++w) va0[w] = 0.0f;
        }
        if (c1 < rbeg){
#pragma unroll
          for (int w = 0; w < 8; ++w) va1[w] = 0.0f;
        }
        for (int r = rbeg + 4 * wv; r < 128; r += 8){
          float p[4][8];
#pragma unroll
          for (int t4 = 0; t4 < 4; ++t4){
            *(float4*)&p[t4][0] = *reinterpret_cast<const float4*>(&cst[r + t4][0]);
            *(float4*)&p[t4][4] = *reinterpret_cast<const float4*>(&cst[r + t4][4]);
          }
          float2 cu[4];
#pragma unroll
          for (int t4 = 0; t4 < 4; ++t4)
            cu[t4] = *reinterpret_cast<float2*>(&As[r + t4][c0]);
#pragma unroll
          for (int t4 = 0; t4 < 4; ++t4){
            float s0 = 0.0f, s1 = 0.0f;
#pragma unroll
            for (int w = 0; w < 8; ++w){ s0 += p[t4][w] * va0[w]; s1 += p[t4][w] * va1[w]; }
            cu[t4].x -= (c0 <= r + t4) ? s0 : 0.0f;
            cu[t4].y -= (c1 <= r + t4) ? s1 : 0.0f;
            *reinterpret_cast<float2*>(&As[r + t4][c0]) = cu[t4];
          }
        }
      } else {
        float vi0[8], vi1[8];
#pragma unroll
        for (int w = 0; w < 8; ++w){
          vi0[w] = (c0 <= j0 + w) ? rst[w][c0] : 0.0f;
          vi1[w] = (c1 <= j0 + w) ? rst[w][c1] : 0.0f;
        }
        for (int r = rbeg + 4 * (wv - 2); r < 128; r += 8){
          float p[4][8];
#pragma unroll
          for (int t4 = 0; t4 < 4; ++t4){
            *(float4*)&p[t4][0] = *reinterpret_cast<const float4*>(&cst[r + t4][0]);
            *(float4*)&p[t4][4] = *reinterpret_cast<const float4*>(&cst[r + t4][4]);
          }
          float2 cu[4];
#pragma unroll
          for (int t4 = 0; t4 < 4; ++t4)
            cu[t4] = *reinterpret_cast<float2*>(&Iv[r + t4][c0]);
#pragma unroll
          for (int t4 = 0; t4 < 4; ++t4){
            float s0 = 0.0f, s1 = 0.0f;
#pragma unroll
            for (int w = 0; w < 8; ++w){ s0 += p[t4][w] * vi0[w]; s1 += p[t4][w] * vi1[w]; }
            cu[t4].x -= s0;
            cu[t4].y -= s1;
            *reinterpret_cast<float2*>(&Iv[r + t4][c0]) = cu[t4];
          }
        }
      }
    }
    __syncthreads();
  }

#pragma unroll
  for (int it = 0; it < 16; ++it){
    int f = it * 1024 + tid * 4;
    int r = f >> 7, c = f & 127;
    float4 a = *reinterpret_cast<const float4*>(&As[r][c]);
    *reinterpret_cast<float4*>(blk + (size_t)r * n + c) = a;
    float4 iv = *reinterpret_cast<const float4*>(&Iv[r][c]);
    if (c + 0 > r) iv.x = 0.0f;
    if (c + 1 > r) iv.y = 0.0f;
    if (c + 2 > r) iv.z = 0.0f;
    if (c + 3 > r) iv.w = 0.0f;
    *reinterpret_cast<float4*>(Linv + (size_t)s * 16384 + f) = iv;
  }
}

// ---------------------------------------------------------------------------
// 3b) panel (kind=0): L21 = A21 * Linv^T ; syrk (kind=1): A_ij -= L_is L_js^T
// ---------------------------------------------------------------------------
__global__ __launch_bounds__(256) void chol_update(float* __restrict__ S,
                                                   const float* __restrict__ Linv,
                                                   int n, int s, int kind){
  __shared__ float At[128][132];
  __shared__ float Bt[128][132];
  const int tid = threadIdx.x;
  const float *A, *B;
  float* C;
  size_t lda, ldb;
  if (kind == 0){
    int i = s + 1 + blockIdx.x;
    A = S + (size_t)i * 128 * n + (size_t)s * 128;  lda = n;
    B = Linv + (size_t)s * 16384;                   ldb = 128;
    C = S + (size_t)i * 128 * n + (size_t)s * 128;
  } else {
    int bb = blockIdx.x;
    int bi, bj; tri_decode(bb, bi, bj);
    int i = s + 1 + bi, jb = s + 1 + bj;
    A = S + (size_t)i * 128 * n + (size_t)s * 128;   lda = n;
    B = S + (size_t)jb * 128 * n + (size_t)s * 128;  ldb = n;
    C = S + (size_t)i * 128 * n + (size_t)jb * 128;
  }
  for (int it = 0; it < 16; ++it){
    int f = it * 256 + tid;
    int r = f >> 5, c4 = (f & 31) * 4;
    float4 va = *reinterpret_cast<const float4*>(A + (size_t)r * lda + c4);
    float4 vb = *reinterpret_cast<const float4*>(B + (size_t)r * ldb + c4);
    At[c4 + 0][r] = va.x; At[c4 + 1][r] = va.y; At[c4 + 2][r] = va.z; At[c4 + 3][r] = va.w;
    Bt[c4 + 0][r] = vb.x; Bt[c4 + 1][r] = vb.y; Bt[c4 + 2][r] = vb.z; Bt[c4 + 3][r] = vb.w;
  }
  __syncthreads();
  const int ty = tid >> 4, tx = tid & 15;
  float accu[8][8];
#pragma unroll
  for (int u = 0; u < 8; ++u)
#pragma unroll
    for (int v = 0; v < 8; ++v) accu[u][v] = 0.0f;
  for (int k = 0; k < 128; ++k){
    float av[8], bv[8];
    *(float4*)&av[0] = *(const float4*)&At[k][ty * 8];
    *(float4*)&av[4] = *(const float4*)&At[k][ty * 8 + 4];
    *(float4*)&bv[0] = *(const float4*)&Bt[k][tx * 8];
    *(float4*)&bv[4] = *(const float4*)&Bt[k][tx * 8 + 4];
#pragma unroll
    for (int u = 0; u < 8; ++u)
#pragma unroll
      for (int v = 0; v < 8; ++v) accu[u][v] += av[u] * bv[v];
  }
  for (int u = 0; u < 8; ++u){
    int r = ty * 8 + u;
    for (int v4 = 0; v4 < 8; v4 += 4){
      int cc = tx * 8 + v4;
      float4 cv;
      if (kind == 1){
        cv = *reinterpret_cast<const float4*>(C + (size_t)r * n + cc);
        cv.x -= accu[u][v4 + 0]; cv.y -= accu[u][v4 + 1];
        cv.z -= accu[u][v4 + 2]; cv.w -= accu[u][v4 + 3];
      } else {
        cv.x = accu[u][v4 + 0]; cv.y = accu[u][v4 + 1];
        cv.z = accu[u][v4 + 2]; cv.w = accu[u][v4 + 3];
      }
      *reinterpret_cast<float4*>(C + (size_t)r * n + cc) = cv;
    }
  }
}

// ---------------------------------------------------------------------------
// 4) T = L^{-1} by recursive bisection (batched level-by-level).
// ---------------------------------------------------------------------------
__global__ void scatter_linv(const float* __restrict__ Linv, float* __restrict__ T, int n){
  int gid = blockIdx.x * 256 + threadIdx.x;
  int s = gid >> 14;
  int idx = gid & 16383;
  int r = idx >> 7, c = idx & 127;
  T[(size_t)(s * 128 + r) * n + s * 128 + c] = Linv[gid];
}

__global__ __launch_bounds__(256) void trtri_gemm(const float* __restrict__ L,
                                                  float* __restrict__ T,
                                                  float* __restrict__ Xb,
                                                  int n, int h, int phase){
  const int tpr = h >> 6;
  const int tpn = tpr * tpr;
  const int node = blockIdx.x / tpn;
  const int t = blockIdx.x - node * tpn;
  const int tr = t / tpr, tc = t - tr * tpr;
  const int base = node * 2 * h;
  const int tid = threadIdx.x;
  const float *A, *Bm;
  float* C;
  size_t lda, ldb, ldc;
  float sign;
  if (phase == 0){
    A   = L + (size_t)(base + h + tr * 64) * n + base;        lda = n;
    Bm  = T + (size_t)base * n + base + tc * 64;              ldb = n;
    C   = Xb + (size_t)node * h * h + (size_t)(tr * 64) * h + tc * 64; ldc = h;
    sign = 1.0f;
  } else {
    A   = T + (size_t)(base + h + tr * 64) * n + (base + h);  lda = n;
    Bm  = Xb + (size_t)node * h * h + tc * 64;                ldb = h;
    C   = T + (size_t)(base + h + tr * 64) * n + base + tc * 64; ldc = n;
    sign = -1.0f;
  }
  __shared__ float At[32][68];
  __shared__ float Bs[32][68];
  const int ty = tid >> 4, tx = tid & 15;
  float accu[4][4];
#pragma unroll
  for (int u = 0; u < 4; ++u)
#pragma unroll
    for (int v = 0; v < 4; ++v) accu[u][v] = 0.0f;
  for (int k0 = 0; k0 < h; k0 += 32){
    __syncthreads();
    for (int it = 0; it < 2; ++it){
      int f = it * 256 + tid;
      int r = f >> 3, c4 = (f & 7) * 4;
      float4 va = *reinterpret_cast<const float4*>(A + (size_t)r * lda + k0 + c4);
      At[c4 + 0][r] = va.x; At[c4 + 1][r] = va.y; At[c4 + 2][r] = va.z; At[c4 + 3][r] = va.w;
    }
    for (int it = 0; it < 2; ++it){
      int f = it * 256 + tid;
      int kk = f >> 4, c4 = (f & 15) * 4;
      float4 vb = *reinterpret_cast<const float4*>(Bm + (size_t)(k0 + kk) * ldb + c4);
      *reinterpret_cast<float4*>(&Bs[kk][c4]) = vb;
    }
    __syncthreads();
    for (int k = 0; k < 32; ++k){
      float av[4], bv[4];
      *(float4*)av = *(const float4*)&At[k][ty * 4];
      *(float4*)bv = *(const float4*)&Bs[k][tx * 4];
#pragma unroll
      for (int u = 0; u < 4; ++u)
#pragma unroll
        for (int v = 0; v < 4; ++v) accu[u][v] += av[u] * bv[v];
    }
  }
  for (int u = 0; u < 4; ++u){
    float4 cv = { sign * accu[u][0], sign * accu[u][1], sign * accu[u][2], sign * accu[u][3] };
    *reinterpret_cast<float4*>(C + (size_t)(ty * 4 + u) * ldc + tx * 4) = cv;
  }
}

// ---------------------------------------------------------------------------
// 5) reductions + final combine
// ---------------------------------------------------------------------------
// trace(inv) = ||T||_F^2 over the lower tile-triangle only (upper-in-block
// parts of diag tiles are exact zeros from scatter_linv).
__global__ void reduce_sq_tri(const float* __restrict__ T, float* __restrict__ scal, int n){
  int t = blockIdx.x;
  int bi, bj; tri_decode(t, bi, bj);          // bi >= bj
  const float* base = T + (size_t)(bi * 128) * n + bj * 128;
  const int tid = threadIdx.x;
  float s = 0.0f;
#pragma unroll
  for (int it = 0; it < 16; ++it){
    int off = it * 1024 + tid * 4;
    int r = off >> 7, c = off & 127;
    float4 v = *reinterpret_cast<const float4*>(base + (size_t)r * n + c);
    s += v.x * v.x + v.y * v.y + v.z * v.z + v.w * v.w;
  }
  for (int off = 32; off; off >>= 1) s += __shfl_down(s, off, 64);
  __shared__ float wsum[4];
  int lane = tid & 63, w = tid >> 6;
  if (lane == 0) wsum[w] = s;
  __syncthreads();
  if (tid == 0) atomicAdd(&scal[0], wsum[0] + wsum[1] + wsum[2] + wsum[3]);
}

__global__ void matvec(const float* __restrict__ T, const float* __restrict__ c,
                       float* __restrict__ y, int n){
  int w = threadIdx.x >> 6, lane = threadIdx.x & 63;
  int row = blockIdx.x * 4 + w;
  if (row >= n) return;
  const float* Tr = T + (size_t)row * n;
  const int kend = ((row >> 7) + 1) << 7;     // T is lower-triangular
  float s = 0.0f;
  for (int k = lane * 4; k < kend; k += 256){
    float4 tv = *reinterpret_cast<const float4*>(Tr + k);
    float4 cv = *reinterpret_cast<const float4*>(c + k);
    s += tv.x * cv.x + tv.y * cv.y + tv.z * cv.z + tv.w * cv.w;
  }
  for (int off = 32; off; off >>= 1) s += __shfl_down(s, off, 64);
  if (lane == 0) y[row] = s;
}

__global__ void final_kernel(const float* __restrict__ S, const float* __restrict__ y,
                             const float* __restrict__ scal, float* __restrict__ out, int n){
  int tid = threadIdx.x;
  float p = 0.0f, ld = 0.0f;
  for (int i = tid; i < n; i += 256){
    float yv = y[i];
    p += yv * yv;
    ld += logf(S[(size_t)i * n + i]);
  }
  for (int off = 32; off; off >>= 1){
    p += __shfl_down(p, off, 64);
    ld += __shfl_down(ld, off, 64);
  }
  __shared__ float sp[4], sl[4];
  int lane = tid & 63, w = tid >> 6;
  if (lane == 0){ sp[w] = p; sl[w] = ld; }
  __syncthreads();
  if (tid == 0){
    float proj = sp[0] + sp[1] + sp[2] + sp[3];
    float lndet = sl[0] + sl[1] + sl[2] + sl[3];
    float ndet = expf((2.0f / (float)n) * lndet);
    float tr = scal[0];
    out[0] = (float)n / 5.0f + ndet * ((0.5f - 1.0f / PI_F) * tr + proj * (1.0f / PI_F));
  }
}

// ---------------------------------------------------------------------------
extern "C" void kernel_launch(void* const* d_in, const int* in_sizes, int n_in,
                              void* d_out, int out_size, void* d_ws, size_t ws_size,
                              hipStream_t stream){
  (void)n_in; (void)out_size;
  const float* X = (const float*)d_in[0];
  const float* c = (const float*)d_in[1];
  const float* alpha = (const float*)d_in[2];
  float* out = (float*)d_out;
  const int n = in_sizes[1];                 // 2048
  const int K = in_sizes[0] / n;             // 16384
  const int tiles = n / 128;                 // 16
  const int TP = tiles * (tiles + 1) / 2;    // 136

  float* S    = (float*)d_ws;                                  // n*n
  float* T    = S + (size_t)n * n;                             // n*n
  float* Xb   = T + (size_t)n * n;                             // (n/2)^2
  float* Linv = Xb + (size_t)(n / 2) * (n / 2);                // tiles*16384
  float* dvec = Linv + (size_t)tiles * 16384;                  // n
  float* y    = dvec + n;                                      // n
  float* scal = y + n;                                         // 16
  size_t base_floats = (size_t)2 * n * n + (size_t)(n / 2) * (n / 2) +
                       (size_t)tiles * 16384 + 2 * (size_t)n + 16;
  size_t need = base_floats * sizeof(float);
  if (ws_size < need) return;

  size_t xbf_off = need;
  size_t xbf_bytes = (size_t)n * (size_t)K * 2;
  bool big = ws_size >= xbf_off + xbf_bytes;
  unsigned short* Xbf = (unsigned short*)((char*)d_ws + xbf_off);

  size_t p_off = xbf_off + xbf_bytes;
  int Ssplit = 0;
  for (int cand = 8; cand >= 2; cand >>= 1){
    size_t pbytes = (size_t)cand * TP * 16384 * sizeof(float);
    if (big && ws_size >= p_off + pbytes && (K % (cand * 64)) == 0){ Ssplit = cand; break; }
  }
  float* P = (float*)((char*)d_ws + p_off);

  hipMemsetAsync(T, 0, (size_t)n * n * sizeof(float), stream);
  hipMemsetAsync(scal, 0, 64, stream);

  // 1) Gram
  if (big){
    long total = (long)n * K;
    convert_bf16<<<(int)(total / 2048), 256, 0, stream>>>(X, Xbf, total);
    if (Ssplit > 0){
      gram_sym<<<TP * Ssplit, 256, 0, stream>>>(Xbf, P, K, TP, Ssplit, K / Ssplit);
      gram_reduce<<<TP, 256, 0, stream>>>(P, S, n, TP, Ssplit, 1.0f / (float)K);
    } else {
      gram_bf16<<<tiles * tiles, 256, 0, stream>>>(Xbf, S, n, K);
    }
  } else {
    gram_kernel<<<tiles * tiles, 256, 0, stream>>>(X, S, n, K);
  }
  // 2) kernel step
  diag_copy<<<(n + 255) / 256, 256, 0, stream>>>(S, dvec, n);
  step_kernel<<<dim3(n / 256, n), 256, 0, stream>>>(S, dvec, alpha, n);
  // 3) Cholesky
  for (int s = 0; s < tiles; ++s){
    chol_diag<<<1, 256, 0, stream>>>(S, Linv, n, s);
    int nb = tiles - 1 - s;
    if (nb > 0){
      chol_update<<<nb, 256, 0, stream>>>(S, Linv, n, s, 0);
      chol_update<<<nb * (nb + 1) / 2, 256, 0, stream>>>(S, Linv, n, s, 1);
    }
  }
  // 4) T = L^{-1}
  scatter_linv<<<tiles * 64, 256, 0, stream>>>(Linv, T, n);
  for (int h = 128; h < n; h <<= 1){
    int nodes = n / (2 * h);
    int grid = nodes * (h / 64) * (h / 64);
    trtri_gemm<<<grid, 256, 0, stream>>>(S, T, Xb, n, h, 0);
    trtri_gemm<<<grid, 256, 0, stream>>>(S, T, Xb, n, h, 1);
  }
  // 5) reductions + combine
  reduce_sq_tri<<<TP, 256, 0, stream>>>(T, scal, n);
  matvec<<<n / 4, 256, 0, stream>>>(T, c, y, n);
  final_kernel<<<1, 256, 0, stream>>>(S, y, scal, out, n);
}

// Round 9
// 2466.184 us; speedup vs baseline: 1.3441x; 1.3441x over previous
//
#include <hip/hip_runtime.h>
#include <math.h>

#define PI_F 3.14159265358979323846f

typedef __attribute__((ext_vector_type(8))) short bf16x8;
typedef __attribute__((ext_vector_type(4))) float f32x4;
typedef __attribute__((ext_vector_type(8))) unsigned short u16x8;

// fp32 -> bf16 round-to-nearest-even
__device__ inline unsigned short f2bf(float f){
  unsigned int b = __float_as_uint(f);
  b += 0x7FFFu + ((b >> 16) & 1u);
  return (unsigned short)(b >> 16);
}

__device__ inline float clamp1(float v){ return fminf(1.0f, fmaxf(-1.0f, v)); }

__device__ inline void tri_decode(int t, int& bi, int& bj){
  bi = (int)((sqrtf(8.0f * t + 1.0f) - 1.0f) * 0.5f);
  while ((bi + 1) * (bi + 2) / 2 <= t) ++bi;
  while (bi * (bi + 1) / 2 > t) --bi;
  bj = t - bi * (bi + 1) / 2;
}

// ---------------------------------------------------------------------------
// 0) X (fp32) -> Xbf (bf16)
// ---------------------------------------------------------------------------
__global__ void convert_bf16(const float* __restrict__ X,
                             unsigned short* __restrict__ Xb, long total){
  long i = ((long)blockIdx.x * 256 + threadIdx.x) * 8;
  if (i >= total) return;
  float4 a = *reinterpret_cast<const float4*>(X + i);
  float4 b = *reinterpret_cast<const float4*>(X + i + 4);
  u16x8 o;
  o[0] = f2bf(a.x); o[1] = f2bf(a.y); o[2] = f2bf(a.z); o[3] = f2bf(a.w);
  o[4] = f2bf(b.x); o[5] = f2bf(b.y); o[6] = f2bf(b.z); o[7] = f2bf(b.w);
  *reinterpret_cast<u16x8*>(Xb + i) = o;
}

// ---------------------------------------------------------------------------
// 1a) Symmetric split-K gram, BK=64, XOR-swizzled LDS (bank-conflict-free,
//     verified: SQ_LDS_BANK_CONFLICT 8.9e6 -> 0).
// ---------------------------------------------------------------------------
__global__ __launch_bounds__(256) void gram_sym(const unsigned short* __restrict__ Xb,
                                                float* __restrict__ P,
                                                int K, int TP, int Ssplit, int Kc){
  const int b = blockIdx.x;
  const int t = b % TP;
  const int s = b / TP;
  int bi, bj; tri_decode(t, bi, bj);
  const int ti = bj, tj = bi;            // ti <= tj
  const int ks0 = s * Kc;

  __shared__ unsigned short Ab[128 * 64];   // 16 KB
  __shared__ unsigned short Bb[128 * 64];
  const int tid = threadIdx.x, lane = tid & 63, w = tid >> 6;
  const int wi = (w >> 1) * 64, wj = (w & 1) * 64;
  const int m16 = lane & 15, q = lane >> 4;

  f32x4 acc[4][4];
#pragma unroll
  for (int a = 0; a < 4; ++a)
#pragma unroll
    for (int b2 = 0; b2 < 4; ++b2) acc[a][b2] = (f32x4){0.f, 0.f, 0.f, 0.f};

  const unsigned short* Ag = Xb + (size_t)(ti * 128) * K;
  const unsigned short* Bg = Xb + (size_t)(tj * 128) * K;
  const int srow = lane >> 3;                       // 0..7
  const int schunk = ((lane & 7) ^ srow) * 8;       // swizzled source chunk

  for (int k0 = ks0; k0 < ks0 + Kc; k0 += 64){
    __syncthreads();
#pragma unroll
    for (int r = 0; r < 4; ++r){
      int row = w * 32 + r * 8 + srow;
      __builtin_amdgcn_global_load_lds(
        (const __attribute__((address_space(1))) void*)(Ag + (size_t)row * K + k0 + schunk),
        (__attribute__((address_space(3))) void*)(Ab + (w * 32 + r * 8) * 64),
        16, 0, 0);
      __builtin_amdgcn_global_load_lds(
        (const __attribute__((address_space(1))) void*)(Bg + (size_t)row * K + k0 + schunk),
        (__attribute__((address_space(3))) void*)(Bb + (w * 32 + r * 8) * 64),
        16, 0, 0);
    }
    __syncthreads();
#pragma unroll
    for (int ks = 0; ks < 2; ++ks){
      bf16x8 af[4], bfr[4];
#pragma unroll
      for (int a = 0; a < 4; ++a){
        int row = wi + a * 16 + m16;
        int ch = ((ks * 4 + q) ^ (row & 7)) * 8;
        af[a] = *reinterpret_cast<const bf16x8*>(&Ab[row * 64 + ch]);
      }
#pragma unroll
      for (int b2 = 0; b2 < 4; ++b2){
        int row = wj + b2 * 16 + m16;
        int ch = ((ks * 4 + q) ^ (row & 7)) * 8;
        bfr[b2] = *reinterpret_cast<const bf16x8*>(&Bb[row * 64 + ch]);
      }
#pragma unroll
      for (int a = 0; a < 4; ++a)
#pragma unroll
        for (int b2 = 0; b2 < 4; ++b2)
          acc[a][b2] = __builtin_amdgcn_mfma_f32_16x16x32_bf16(af[a], bfr[b2], acc[a][b2], 0, 0, 0);
    }
  }

  float* Pt = P + ((size_t)(s * TP + t) << 14);
#pragma unroll
  for (int a = 0; a < 4; ++a)
#pragma unroll
    for (int b2 = 0; b2 < 4; ++b2)
#pragma unroll
      for (int r = 0; r < 4; ++r){
        int row = wi + a * 16 + q * 4 + r;
        int col = wj + b2 * 16 + m16;
        Pt[row * 128 + col] = acc[a][b2][r];
      }
}

// Sum partials, scale+clamp, write tile and (via LDS transpose) its mirror.
__global__ __launch_bounds__(256) void gram_reduce(const float* __restrict__ P,
                                                   float* __restrict__ S,
                                                   int n, int TP, int Ssplit,
                                                   float invK){
  const int t = blockIdx.x;
  int bi, bj; tri_decode(t, bi, bj);
  const int ti = bj, tj = bi;
  const int tid = threadIdx.x;
  __shared__ float Ls[128][129];
  const float* Pt = P + ((size_t)t << 14);
  const size_t pstride = (size_t)TP << 14;
#pragma unroll
  for (int it = 0; it < 16; ++it){
    int off = it * 1024 + tid * 4;
    int r = off >> 7, c = off & 127;
    float4 v = *reinterpret_cast<const float4*>(Pt + off);
    for (int s = 1; s < Ssplit; ++s){
      float4 u = *reinterpret_cast<const float4*>(Pt + s * pstride + off);
      v.x += u.x; v.y += u.y; v.z += u.z; v.w += u.w;
    }
    v.x = clamp1(v.x * invK); v.y = clamp1(v.y * invK);
    v.z = clamp1(v.z * invK); v.w = clamp1(v.w * invK);
    *reinterpret_cast<float4*>(S + (size_t)(ti * 128 + r) * n + tj * 128 + c) = v;
    *reinterpret_cast<float4*>(&Ls[r][c]) = v;
  }
  if (ti == tj) return;
  __syncthreads();
#pragma unroll
  for (int it = 0; it < 16; ++it){
    int off = it * 1024 + tid * 4;
    int m = off >> 7, cc = off & 127;
    float4 v = { Ls[cc + 0][m], Ls[cc + 1][m], Ls[cc + 2][m], Ls[cc + 3][m] };
    *reinterpret_cast<float4*>(S + (size_t)(tj * 128 + m) * n + ti * 128 + cc) = v;
  }
}

// ---------------------------------------------------------------------------
// 1b) Monolithic gram from bf16 (fallback when partial buffers don't fit).
// ---------------------------------------------------------------------------
__global__ __launch_bounds__(256) void gram_bf16(const unsigned short* __restrict__ Xb,
                                                 float* __restrict__ S, int n, int K){
  const int tiles = n >> 7;
  int b = blockIdx.x, ti, tj;
  if (tiles == 16){
    int xcd = b & 7, s2 = b >> 3;
    ti = ((xcd >> 1) << 2) | (s2 & 3);
    tj = ((xcd & 1) << 3) | (s2 >> 2);
  } else { ti = b / tiles; tj = b - ti * tiles; }

  __shared__ unsigned short Ab[128 * 32];
  __shared__ unsigned short Bb[128 * 32];
  const int tid = threadIdx.x, lane = tid & 63, w = tid >> 6;
  const int wi = (w >> 1) * 64, wj = (w & 1) * 64;
  const int m16 = lane & 15, q = lane >> 4;

  f32x4 acc[4][4];
#pragma unroll
  for (int a = 0; a < 4; ++a)
#pragma unroll
    for (int b2 = 0; b2 < 4; ++b2) acc[a][b2] = (f32x4){0.f, 0.f, 0.f, 0.f};

  const unsigned short* Ag = Xb + (size_t)(ti * 128) * K;
  const unsigned short* Bg = Xb + (size_t)(tj * 128) * K;
  const int srow = lane >> 2;
  const int scol = (lane & 3) * 8;

  for (int k0 = 0; k0 < K; k0 += 32){
    __syncthreads();
#pragma unroll
    for (int r = 0; r < 2; ++r){
      int row = w * 32 + r * 16 + srow;
      __builtin_amdgcn_global_load_lds(
        (const __attribute__((address_space(1))) void*)(Ag + (size_t)row * K + k0 + scol),
        (__attribute__((address_space(3))) void*)(Ab + w * 1024 + r * 512),
        16, 0, 0);
      __builtin_amdgcn_global_load_lds(
        (const __attribute__((address_space(1))) void*)(Bg + (size_t)row * K + k0 + scol),
        (__attribute__((address_space(3))) void*)(Bb + w * 1024 + r * 512),
        16, 0, 0);
    }
    __syncthreads();
    bf16x8 af[4], bfr[4];
#pragma unroll
    for (int a = 0; a < 4; ++a)
      af[a] = *reinterpret_cast<const bf16x8*>(&Ab[(wi + a * 16 + m16) * 32 + q * 8]);
#pragma unroll
    for (int b2 = 0; b2 < 4; ++b2)
      bfr[b2] = *reinterpret_cast<const bf16x8*>(&Bb[(wj + b2 * 16 + m16) * 32 + q * 8]);
#pragma unroll
    for (int a = 0; a < 4; ++a)
#pragma unroll
      for (int b2 = 0; b2 < 4; ++b2)
        acc[a][b2] = __builtin_amdgcn_mfma_f32_16x16x32_bf16(af[a], bfr[b2], acc[a][b2], 0, 0, 0);
  }

  const float invK = 1.0f / (float)K;
#pragma unroll
  for (int a = 0; a < 4; ++a)
#pragma unroll
    for (int b2 = 0; b2 < 4; ++b2)
#pragma unroll
      for (int r = 0; r < 4; ++r){
        int row = ti * 128 + wi + a * 16 + q * 4 + r;
        int col = tj * 128 + wj + b2 * 16 + m16;
        S[(size_t)row * n + col] = clamp1(acc[a][b2][r] * invK);
      }
}

// ---------------------------------------------------------------------------
// 1c) Fallback gram (fp32 input, in-kernel conversion).
// ---------------------------------------------------------------------------
__global__ __launch_bounds__(256) void gram_kernel(const float* __restrict__ X,
                                                   float* __restrict__ S,
                                                   int n, int K){
  const int tiles = n >> 7;
  int b = blockIdx.x, ti, tj;
  ti = b / tiles; tj = b - ti * tiles;

  __shared__ unsigned short Ab[128 * 32];
  __shared__ unsigned short Bb[128 * 32];

  const int tid = threadIdx.x;
  const int lane = tid & 63;
  const int w = tid >> 6;
  const int wi = (w >> 1) * 64, wj = (w & 1) * 64;
  const int m16 = lane & 15, q = lane >> 4;

  f32x4 acc[4][4];
#pragma unroll
  for (int a = 0; a < 4; ++a)
#pragma unroll
    for (int b2 = 0; b2 < 4; ++b2) acc[a][b2] = (f32x4){0.f, 0.f, 0.f, 0.f};

  const float* Abase = X + (size_t)ti * 128 * K;
  const float* Bbase = X + (size_t)tj * 128 * K;
  const int strow = tid >> 3;
  const int stc = (tid & 7) * 4;

  float4 ra[4], rb[4];
  for (int k0 = 0; k0 < K; k0 += 32){
#pragma unroll
    for (int r = 0; r < 4; ++r){
      int row = r * 32 + strow;
      ra[r] = *reinterpret_cast<const float4*>(Abase + (size_t)row * K + k0 + stc);
      rb[r] = *reinterpret_cast<const float4*>(Bbase + (size_t)row * K + k0 + stc);
    }
    __syncthreads();
#pragma unroll
    for (int r = 0; r < 4; ++r){
      int row = r * 32 + strow;
      int base = row * 32 + stc;
      ushort4 ua, ub;
      ua.x = f2bf(ra[r].x); ua.y = f2bf(ra[r].y); ua.z = f2bf(ra[r].z); ua.w = f2bf(ra[r].w);
      ub.x = f2bf(rb[r].x); ub.y = f2bf(rb[r].y); ub.z = f2bf(rb[r].z); ub.w = f2bf(rb[r].w);
      *reinterpret_cast<ushort4*>(&Ab[base]) = ua;
      *reinterpret_cast<ushort4*>(&Bb[base]) = ub;
    }
    __syncthreads();
    bf16x8 af[4], bfv[4];
#pragma unroll
    for (int a = 0; a < 4; ++a)
      af[a] = *reinterpret_cast<const bf16x8*>(&Ab[(wi + a * 16 + m16) * 32 + q * 8]);
#pragma unroll
    for (int b2 = 0; b2 < 4; ++b2)
      bfv[b2] = *reinterpret_cast<const bf16x8*>(&Bb[(wj + b2 * 16 + m16) * 32 + q * 8]);
#pragma unroll
    for (int a = 0; a < 4; ++a)
#pragma unroll
      for (int b2 = 0; b2 < 4; ++b2)
        acc[a][b2] = __builtin_amdgcn_mfma_f32_16x16x32_bf16(af[a], bfv[b2], acc[a][b2], 0, 0, 0);
  }

  const float invK = 1.0f / (float)K;
#pragma unroll
  for (int a = 0; a < 4; ++a)
#pragma unroll
    for (int b2 = 0; b2 < 4; ++b2)
#pragma unroll
      for (int r = 0; r < 4; ++r){
        int row = ti * 128 + wi + a * 16 + q * 4 + r;
        int col = tj * 128 + wj + b2 * 16 + m16;
        S[(size_t)row * n + col] = clamp1(acc[a][b2][r] * invK);
      }
}

// ---------------------------------------------------------------------------
// 2) arc-cosine kernel step
// ---------------------------------------------------------------------------
__global__ void diag_copy(const float* __restrict__ S, float* __restrict__ d, int n){
  int i = blockIdx.x * blockDim.x + threadIdx.x;
  if (i < n) d[i] = S[(size_t)i * n + i];
}

__global__ void step_kernel(float* __restrict__ S, const float* __restrict__ d,
                            const float* __restrict__ alphap, int n){
  int j = blockIdx.x * blockDim.x + threadIdx.x;
  int i = blockIdx.y;
  if (j >= n) return;
  float a2 = alphap[0] * alphap[0];
  size_t idx = (size_t)i * n + j;
  float s = S[idx];
  float cross = sqrtf(d[i] * d[j]);
  float m = clamp1(s / cross);
  float qq = 1.0f - m * m;
  float sq, ac;
  if (qq > 0.0f){ sq = sqrtf(qq); ac = acosf(m); }
  else          { sq = 0.0f;      ac = (m > 0.0f) ? 0.0f : PI_F; }
  float f = (sq + m * (PI_F - ac)) / PI_F;
  float t = cross * f;
  S[idx] = clamp1((s + a2 * t) / (1.0f + a2));
}

// ---------------------------------------------------------------------------
// 3a) Cholesky diagonal block v4 — register-lean stage.
//     The rank-8 stage no longer computes a redundant 8x8 Cholesky per
//     thread (T[8][8] = 64 VGPRs; prime suspect for scratch spills that kept
//     rounds 4-8 pinned at ~140-150 us regardless of sweep shape). Instead:
//     wave 0 computes it ONCE, lane-per-row with __shfl broadcasts, and
//     publishes Ts[8][9]+invds[8] via LDS; the fwd-subst / GJ chains read Ts
//     as broadcast LDS loads (max ~50 live VGPRs). Sweep = round-5 measured
//     best shape: 1024 threads, 8 groups (4 row-phases x {As, Iv}).
// ---------------------------------------------------------------------------
__global__ __launch_bounds__(1024) void chol_diag(float* __restrict__ S,
                                                  float* __restrict__ Linv,
                                                  int n, int s){
  __shared__ float As[128][132];
  __shared__ float Iv[128][132];
  __shared__ __align__(16) float cst[128][12];
  __shared__ float rst[8][128];
  __shared__ float Ts[8][9];
  __shared__ float invds[8];
  const int tid = threadIdx.x;
  float* blk = S + (size_t)s * 128 * n + (size_t)s * 128;
#pragma unroll
  for (int it = 0; it < 4; ++it){
    int f = it * 4096 + tid * 4;
    int r = f >> 7, c = f & 127;
    float4 v = *reinterpret_cast<const float4*>(blk + (size_t)r * n + c);
    *reinterpret_cast<float4*>(&As[r][c]) = v;
    float4 e = {0.f, 0.f, 0.f, 0.f};
    if (r >= c && r < c + 4) ((float*)&e)[r - c] = 1.0f;
    *reinterpret_cast<float4*>(&Iv[r][c]) = e;
  }
  __syncthreads();

  const int ct = tid & 127;
  const int g = tid >> 7;        // 0..7
  const int rg = g & 3;
  const int isIv = g >> 2;

  for (int b = 0; b < 16; ++b){
    const int j0 = b * 8;
    // ---- PHASE 1: 8x8 Cholesky, wave-parallel on wave 0 ----
    if (tid < 64){
      const int u = tid & 7;
      const int gb = tid & 56;
      float t[8];
#pragma unroll
      for (int w = 0; w < 8; ++w) t[w] = (w <= u) ? As[j0 + u][j0 + w] : 0.0f;
      float ivd[8];
#pragma unroll
      for (int w = 0; w < 8; ++w){
        float dv = sqrtf(__shfl(t[w], gb + w, 64));
        float iv = 1.0f / dv;
        ivd[w] = iv;
        t[w] = (u == w) ? dv : ((u > w) ? t[w] * iv : t[w]);
#pragma unroll
        for (int v = w + 1; v < 8; ++v){
          float Tvw = __shfl(t[w], gb + v, 64);
          if (v <= u) t[v] -= t[w] * Tvw;
        }
      }
      if (tid < 8){
#pragma unroll
        for (int w = 0; w < 8; ++w) Ts[u][w] = (w <= u) ? t[w] : 0.0f;
        invds[u] = ivd[u];
      }
    }
    __syncthreads();
    // ---- PHASE 2: chains (threads 0..255) ----
    if (tid < 256){
      if (tid < 128){
        int r = tid;
        if (r >= j0){
          float l[8];
          if (r < j0 + 8){
            int p = r - j0;
#pragma unroll
            for (int w = 0; w < 8; ++w) l[w] = Ts[p][w];
          } else {
            *(float4*)&l[0] = *reinterpret_cast<const float4*>(&As[r][j0]);
            *(float4*)&l[4] = *reinterpret_cast<const float4*>(&As[r][j0 + 4]);
#pragma unroll
            for (int w = 0; w < 8; ++w){
#pragma unroll
              for (int u = 0; u < 8; ++u) if (u < w) l[w] -= l[u] * Ts[w][u];
              l[w] *= invds[w];
            }
          }
#pragma unroll
          for (int w = 0; w < 8; ++w){ cst[r][w] = l[w]; As[r][j0 + w] = l[w]; }
        }
      } else {
        int c = tid - 128;
        float yv[8];
#pragma unroll
        for (int w = 0; w < 8; ++w) yv[w] = Iv[j0 + w][c];
#pragma unroll
        for (int w = 0; w < 8; ++w){
#pragma unroll
          for (int u = 0; u < 8; ++u) if (u < w) yv[w] -= Ts[w][u] * yv[u];
          yv[w] *= invds[w];
        }
#pragma unroll
        for (int w = 0; w < 8; ++w){
          rst[w][c] = yv[w];
          if (c <= j0 + w) Iv[j0 + w][c] = yv[w];
        }
      }
    }
    __syncthreads();
    // ---- PHASE 3: SWEEP (all 1024 threads, round-5 shape) ----
    if (j0 + 8 < 128){
      if (!isIv){
        float v0 = 0.f, v1 = 0.f, v2 = 0.f, v3 = 0.f, v4 = 0.f, v5 = 0.f, v6 = 0.f, v7 = 0.f;
        if (ct >= j0 + 8){
          v0 = cst[ct][0]; v1 = cst[ct][1]; v2 = cst[ct][2]; v3 = cst[ct][3];
          v4 = cst[ct][4]; v5 = cst[ct][5]; v6 = cst[ct][6]; v7 = cst[ct][7];
        }
        for (int r = j0 + 8 + rg; r < 128; r += 4){
          float4 p0 = *reinterpret_cast<const float4*>(&cst[r][0]);
          float4 p1 = *reinterpret_cast<const float4*>(&cst[r][4]);
          float sub = p0.x * v0 + p0.y * v1 + p0.z * v2 + p0.w * v3
                    + p1.x * v4 + p1.y * v5 + p1.z * v6 + p1.w * v7;
          float subm = (ct <= r) ? sub : 0.0f;
          As[r][ct] -= subm;
        }
      } else {
        float v0 = (ct <= j0 + 0) ? rst[0][ct] : 0.0f;
        float v1 = (ct <= j0 + 1) ? rst[1][ct] : 0.0f;
        float v2 = (ct <= j0 + 2) ? rst[2][ct] : 0.0f;
        float v3 = (ct <= j0 + 3) ? rst[3][ct] : 0.0f;
        float v4 = (ct <= j0 + 4) ? rst[4][ct] : 0.0f;
        float v5 = (ct <= j0 + 5) ? rst[5][ct] : 0.0f;
        float v6 = (ct <= j0 + 6) ? rst[6][ct] : 0.0f;
        float v7 = (ct <= j0 + 7) ? rst[7][ct] : 0.0f;
        for (int r = j0 + 8 + rg; r < 128; r += 4){
          float4 p0 = *reinterpret_cast<const float4*>(&cst[r][0]);
          float4 p1 = *reinterpret_cast<const float4*>(&cst[r][4]);
          float sub = p0.x * v0 + p0.y * v1 + p0.z * v2 + p0.w * v3
                    + p1.x * v4 + p1.y * v5 + p1.z * v6 + p1.w * v7;
          Iv[r][ct] -= sub;
        }
      }
    }
    __syncthreads();
  }

#pragma unroll
  for (int it = 0; it < 4; ++it){
    int f = it * 4096 + tid * 4;
    int r = f >> 7, c = f & 127;
    float4 a = *reinterpret_cast<const float4*>(&As[r][c]);
    *reinterpret_cast<float4*>(blk + (size_t)r * n + c) = a;
    float4 iv = *reinterpret_cast<const float4*>(&Iv[r][c]);
    if (c + 0 > r) iv.x = 0.0f;
    if (c + 1 > r) iv.y = 0.0f;
    if (c + 2 > r) iv.z = 0.0f;
    if (c + 3 > r) iv.w = 0.0f;
    *reinterpret_cast<float4*>(Linv + (size_t)s * 16384 + f) = iv;
  }
}

// ---------------------------------------------------------------------------
// 3b) panel (kind=0): L21 = A21 * Linv^T ; syrk (kind=1): A_ij -= L_is L_js^T
// ---------------------------------------------------------------------------
__global__ __launch_bounds__(256) void chol_update(float* __restrict__ S,
                                                   const float* __restrict__ Linv,
                                                   int n, int s, int kind){
  __shared__ float At[128][132];
  __shared__ float Bt[128][132];
  const int tid = threadIdx.x;
  const float *A, *B;
  float* C;
  size_t lda, ldb;
  if (kind == 0){
    int i = s + 1 + blockIdx.x;
    A = S + (size_t)i * 128 * n + (size_t)s * 128;  lda = n;
    B = Linv + (size_t)s * 16384;                   ldb = 128;
    C = S + (size_t)i * 128 * n + (size_t)s * 128;
  } else {
    int bb = blockIdx.x;
    int bi, bj; tri_decode(bb, bi, bj);
    int i = s + 1 + bi, jb = s + 1 + bj;
    A = S + (size_t)i * 128 * n + (size_t)s * 128;   lda = n;
    B = S + (size_t)jb * 128 * n + (size_t)s * 128;  ldb = n;
    C = S + (size_t)i * 128 * n + (size_t)jb * 128;
  }
  for (int it = 0; it < 16; ++it){
    int f = it * 256 + tid;
    int r = f >> 5, c4 = (f & 31) * 4;
    float4 va = *reinterpret_cast<const float4*>(A + (size_t)r * lda + c4);
    float4 vb = *reinterpret_cast<const float4*>(B + (size_t)r * ldb + c4);
    At[c4 + 0][r] = va.x; At[c4 + 1][r] = va.y; At[c4 + 2][r] = va.z; At[c4 + 3][r] = va.w;
    Bt[c4 + 0][r] = vb.x; Bt[c4 + 1][r] = vb.y; Bt[c4 + 2][r] = vb.z; Bt[c4 + 3][r] = vb.w;
  }
  __syncthreads();
  const int ty = tid >> 4, tx = tid & 15;
  float accu[8][8];
#pragma unroll
  for (int u = 0; u < 8; ++u)
#pragma unroll
    for (int v = 0; v < 8; ++v) accu[u][v] = 0.0f;
  for (int k = 0; k < 128; ++k){
    float av[8], bv[8];
    *(float4*)&av[0] = *(const float4*)&At[k][ty * 8];
    *(float4*)&av[4] = *(const float4*)&At[k][ty * 8 + 4];
    *(float4*)&bv[0] = *(const float4*)&Bt[k][tx * 8];
    *(float4*)&bv[4] = *(const float4*)&Bt[k][tx * 8 + 4];
#pragma unroll
    for (int u = 0; u < 8; ++u)
#pragma unroll
      for (int v = 0; v < 8; ++v) accu[u][v] += av[u] * bv[v];
  }
  for (int u = 0; u < 8; ++u){
    int r = ty * 8 + u;
    for (int v4 = 0; v4 < 8; v4 += 4){
      int cc = tx * 8 + v4;
      float4 cv;
      if (kind == 1){
        cv = *reinterpret_cast<const float4*>(C + (size_t)r * n + cc);
        cv.x -= accu[u][v4 + 0]; cv.y -= accu[u][v4 + 1];
        cv.z -= accu[u][v4 + 2]; cv.w -= accu[u][v4 + 3];
      } else {
        cv.x = accu[u][v4 + 0]; cv.y = accu[u][v4 + 1];
        cv.z = accu[u][v4 + 2]; cv.w = accu[u][v4 + 3];
      }
      *reinterpret_cast<float4*>(C + (size_t)r * n + cc) = cv;
    }
  }
}

// ---------------------------------------------------------------------------
// 4) T = L^{-1} by recursive bisection (batched level-by-level).
// ---------------------------------------------------------------------------
__global__ void scatter_linv(const float* __restrict__ Linv, float* __restrict__ T, int n){
  int gid = blockIdx.x * 256 + threadIdx.x;
  int s = gid >> 14;
  int idx = gid & 16383;
  int r = idx >> 7, c = idx & 127;
  T[(size_t)(s * 128 + r) * n + s * 128 + c] = Linv[gid];
}

__global__ __launch_bounds__(256) void trtri_gemm(const float* __restrict__ L,
                                                  float* __restrict__ T,
                                                  float* __restrict__ Xb,
                                                  int n, int h, int phase){
  const int tpr = h >> 6;
  const int tpn = tpr * tpr;
  const int node = blockIdx.x / tpn;
  const int t = blockIdx.x - node * tpn;
  const int tr = t / tpr, tc = t - tr * tpr;
  const int base = node * 2 * h;
  const int tid = threadIdx.x;
  const float *A, *Bm;
  float* C;
  size_t lda, ldb, ldc;
  float sign;
  if (phase == 0){
    A   = L + (size_t)(base + h + tr * 64) * n + base;        lda = n;
    Bm  = T + (size_t)base * n + base + tc * 64;              ldb = n;
    C   = Xb + (size_t)node * h * h + (size_t)(tr * 64) * h + tc * 64; ldc = h;
    sign = 1.0f;
  } else {
    A   = T + (size_t)(base + h + tr * 64) * n + (base + h);  lda = n;
    Bm  = Xb + (size_t)node * h * h + tc * 64;                ldb = h;
    C   = T + (size_t)(base + h + tr * 64) * n + base + tc * 64; ldc = n;
    sign = -1.0f;
  }
  __shared__ float At[32][68];
  __shared__ float Bs[32][68];
  const int ty = tid >> 4, tx = tid & 15;
  float accu[4][4];
#pragma unroll
  for (int u = 0; u < 4; ++u)
#pragma unroll
    for (int v = 0; v < 4; ++v) accu[u][v] = 0.0f;
  for (int k0 = 0; k0 < h; k0 += 32){
    __syncthreads();
    for (int it = 0; it < 2; ++it){
      int f = it * 256 + tid;
      int r = f >> 3, c4 = (f & 7) * 4;
      float4 va = *reinterpret_cast<const float4*>(A + (size_t)r * lda + k0 + c4);
      At[c4 + 0][r] = va.x; At[c4 + 1][r] = va.y; At[c4 + 2][r] = va.z; At[c4 + 3][r] = va.w;
    }
    for (int it = 0; it < 2; ++it){
      int f = it * 256 + tid;
      int kk = f >> 4, c4 = (f & 15) * 4;
      float4 vb = *reinterpret_cast<const float4*>(Bm + (size_t)(k0 + kk) * ldb + c4);
      *reinterpret_cast<float4*>(&Bs[kk][c4]) = vb;
    }
    __syncthreads();
    for (int k = 0; k < 32; ++k){
      float av[4], bv[4];
      *(float4*)av = *(const float4*)&At[k][ty * 4];
      *(float4*)bv = *(const float4*)&Bs[k][tx * 4];
#pragma unroll
      for (int u = 0; u < 4; ++u)
#pragma unroll
        for (int v = 0; v < 4; ++v) accu[u][v] += av[u] * bv[v];
    }
  }
  for (int u = 0; u < 4; ++u){
    float4 cv = { sign * accu[u][0], sign * accu[u][1], sign * accu[u][2], sign * accu[u][3] };
    *reinterpret_cast<float4*>(C + (size_t)(ty * 4 + u) * ldc + tx * 4) = cv;
  }
}

// ---------------------------------------------------------------------------
// 5) reductions + final combine
// ---------------------------------------------------------------------------
__global__ void reduce_sq_tri(const float* __restrict__ T, float* __restrict__ scal, int n){
  int t = blockIdx.x;
  int bi, bj; tri_decode(t, bi, bj);          // bi >= bj
  const float* base = T + (size_t)(bi * 128) * n + bj * 128;
  const int tid = threadIdx.x;
  float s = 0.0f;
#pragma unroll
  for (int it = 0; it < 16; ++it){
    int off = it * 1024 + tid * 4;
    int r = off >> 7, c = off & 127;
    float4 v = *reinterpret_cast<const float4*>(base + (size_t)r * n + c);
    s += v.x * v.x + v.y * v.y + v.z * v.z + v.w * v.w;
  }
  for (int off = 32; off; off >>= 1) s += __shfl_down(s, off, 64);
  __shared__ float wsum[4];
  int lane = tid & 63, w = tid >> 6;
  if (lane == 0) wsum[w] = s;
  __syncthreads();
  if (tid == 0) atomicAdd(&scal[0], wsum[0] + wsum[1] + wsum[2] + wsum[3]);
}

__global__ void matvec(const float* __restrict__ T, const float* __restrict__ c,
                       float* __restrict__ y, int n){
  int w = threadIdx.x >> 6, lane = threadIdx.x & 63;
  int row = blockIdx.x * 4 + w;
  if (row >= n) return;
  const float* Tr = T + (size_t)row * n;
  const int kend = ((row >> 7) + 1) << 7;     // T is lower-triangular
  float s = 0.0f;
  for (int k = lane * 4; k < kend; k += 256){
    float4 tv = *reinterpret_cast<const float4*>(Tr + k);
    float4 cv = *reinterpret_cast<const float4*>(c + k);
    s += tv.x * cv.x + tv.y * cv.y + tv.z * cv.z + tv.w * cv.w;
  }
  for (int off = 32; off; off >>= 1) s += __shfl_down(s, off, 64);
  if (lane == 0) y[row] = s;
}

__global__ void final_kernel(const float* __restrict__ S, const float* __restrict__ y,
                             const float* __restrict__ scal, float* __restrict__ out, int n){
  int tid = threadIdx.x;
  float p = 0.0f, ld = 0.0f;
  for (int i = tid; i < n; i += 256){
    float yv = y[i];
    p += yv * yv;
    ld += logf(S[(size_t)i * n + i]);
  }
  for (int off = 32; off; off >>= 1){
    p += __shfl_down(p, off, 64);
    ld += __shfl_down(ld, off, 64);
  }
  __shared__ float sp[4], sl[4];
  int lane = tid & 63, w = tid >> 6;
  if (lane == 0){ sp[w] = p; sl[w] = ld; }
  __syncthreads();
  if (tid == 0){
    float proj = sp[0] + sp[1] + sp[2] + sp[3];
    float lndet = sl[0] + sl[1] + sl[2] + sl[3];
    float ndet = expf((2.0f / (float)n) * lndet);
    float tr = scal[0];
    out[0] = (float)n / 5.0f + ndet * ((0.5f - 1.0f / PI_F) * tr + proj * (1.0f / PI_F));
  }
}

// ---------------------------------------------------------------------------
extern "C" void kernel_launch(void* const* d_in, const int* in_sizes, int n_in,
                              void* d_out, int out_size, void* d_ws, size_t ws_size,
                              hipStream_t stream){
  (void)n_in; (void)out_size;
  const float* X = (const float*)d_in[0];
  const float* c = (const float*)d_in[1];
  const float* alpha = (const float*)d_in[2];
  float* out = (float*)d_out;
  const int n = in_sizes[1];                 // 2048
  const int K = in_sizes[0] / n;             // 16384
  const int tiles = n / 128;                 // 16
  const int TP = tiles * (tiles + 1) / 2;    // 136

  float* S    = (float*)d_ws;                                  // n*n
  float* T    = S + (size_t)n * n;                             // n*n
  float* Xb   = T + (size_t)n * n;                             // (n/2)^2
  float* Linv = Xb + (size_t)(n / 2) * (n / 2);                // tiles*16384
  float* dvec = Linv + (size_t)tiles * 16384;                  // n
  float* y    = dvec + n;                                      // n
  float* scal = y + n;                                         // 16
  size_t base_floats = (size_t)2 * n * n + (size_t)(n / 2) * (n / 2) +
                       (size_t)tiles * 16384 + 2 * (size_t)n + 16;
  size_t need = base_floats * sizeof(float);
  if (ws_size < need) return;

  size_t xbf_off = need;
  size_t xbf_bytes = (size_t)n * (size_t)K * 2;
  bool big = ws_size >= xbf_off + xbf_bytes;
  unsigned short* Xbf = (unsigned short*)((char*)d_ws + xbf_off);

  size_t p_off = xbf_off + xbf_bytes;
  int Ssplit = 0;
  for (int cand = 8; cand >= 2; cand >>= 1){
    size_t pbytes = (size_t)cand * TP * 16384 * sizeof(float);
    if (big && ws_size >= p_off + pbytes && (K % (cand * 64)) == 0){ Ssplit = cand; break; }
  }
  float* P = (float*)((char*)d_ws + p_off);

  hipMemsetAsync(T, 0, (size_t)n * n * sizeof(float), stream);
  hipMemsetAsync(scal, 0, 64, stream);

  // 1) Gram
  if (big){
    long total = (long)n * K;
    convert_bf16<<<(int)(total / 2048), 256, 0, stream>>>(X, Xbf, total);
    if (Ssplit > 0){
      gram_sym<<<TP * Ssplit, 256, 0, stream>>>(Xbf, P, K, TP, Ssplit, K / Ssplit);
      gram_reduce<<<TP, 256, 0, stream>>>(P, S, n, TP, Ssplit, 1.0f / (float)K);
    } else {
      gram_bf16<<<tiles * tiles, 256, 0, stream>>>(Xbf, S, n, K);
    }
  } else {
    gram_kernel<<<tiles * tiles, 256, 0, stream>>>(X, S, n, K);
  }
  // 2) kernel step
  diag_copy<<<(n + 255) / 256, 256, 0, stream>>>(S, dvec, n);
  step_kernel<<<dim3(n / 256, n), 256, 0, stream>>>(S, dvec, alpha, n);
  // 3) Cholesky
  for (int s = 0; s < tiles; ++s){
    chol_diag<<<1, 1024, 0, stream>>>(S, Linv, n, s);
    int nb = tiles - 1 - s;
    if (nb > 0){
      chol_update<<<nb, 256, 0, stream>>>(S, Linv, n, s, 0);
      chol_update<<<nb * (nb + 1) / 2, 256, 0, stream>>>(S, Linv, n, s, 1);
    }
  }
  // 4) T = L^{-1}
  scatter_linv<<<tiles * 64, 256, 0, stream>>>(Linv, T, n);
  for (int h = 128; h < n; h <<= 1){
    int nodes = n / (2 * h);
    int grid = nodes * (h / 64) * (h / 64);
    trtri_gemm<<<grid, 256, 0, stream>>>(S, T, Xb, n, h, 0);
    trtri_gemm<<<grid, 256, 0, stream>>>(S, T, Xb, n, h, 1);
  }
  // 5) reductions + combine
  reduce_sq_tri<<<TP, 256, 0, stream>>>(T, scal, n);
  matvec<<<n / 4, 256, 0, stream>>>(T, c, y, n);
  final_kernel<<<1, 256, 0, stream>>>(S, y, scal, out, n);
}